// Round 7
// baseline (124.386 us; speedup 1.0000x reference)
//
#include <hip/hip_runtime.h>
#include <hip/hip_bf16.h>

typedef __bf16 bf16x2_t __attribute__((ext_vector_type(2)));
typedef __bf16 bf16x8_t __attribute__((ext_vector_type(8)));
typedef float f32x4 __attribute__((ext_vector_type(4)));

#define BATCH   8
#define LENGTH  4096
#define KHALF   128
#define MTOT    (BATCH*LENGTH)
#define NCHUNK  128
#define LC      32

// 16B-chunk XOR swizzle: chunk index ^ (row & 7). Keeps b128 frag reads and
// bf16x2 scan accesses at <=2-way bank conflict with ZERO padding.
#define SWZ(ch, row) ((ch) ^ ((row) & 7))

// ---------------- transpose B, C to bf16 ----------------
__global__ __launch_bounds__(256) void transpose_bc(
    const float* __restrict__ Bsrc, const float* __restrict__ Csrc,
    __bf16* __restrict__ BT, __bf16* __restrict__ CT) {
  const float* src = blockIdx.y ? Csrc : Bsrc;
  __bf16* dst      = blockIdx.y ? CT   : BT;
  int n  = blockIdx.x;
  int kk = threadIdx.x;
  dst[n * 256 + kk] = (__bf16)src[kk * 256 + n];
}

// ---------------- GEMM1: uB = u @ B (64x256 tile, full N), fused chunk-partial scan ----
__global__ __launch_bounds__(256) void gemm1_fused(
    const float* __restrict__ u, const __bf16* __restrict__ BT,
    const float* __restrict__ Aarr,
    __bf16* __restrict__ uB, float2* __restrict__ P) {
  __shared__ __align__(16) __bf16 sA[64 * 256];   // 32 KB

  const int tid  = threadIdx.x;
  const int lane = tid & 63;
  const int wave = tid >> 6;          // column group (0..3)
  const int m_l  = lane & 15, quad = lane >> 4;
  const int m0   = blockIdx.x * 64;
  const int b    = m0 >> 12;
  const int t0   = m0 & 4095;

  // stage u (fp32 -> bf16), swizzled 16B chunks
#pragma unroll
  for (int i = 0; i < 8; ++i) {
    int s   = tid + i * 256;          // 0..2047 chunks of 8 cols
    int row = s >> 5, ch = s & 31;
    const float4* g = (const float4*)(u + (size_t)(m0 + row) * 256 + ch * 8);
    float4 a = g[0], c = g[1];
    bf16x8_t v;
    v[0]=(__bf16)a.x; v[1]=(__bf16)a.y; v[2]=(__bf16)a.z; v[3]=(__bf16)a.w;
    v[4]=(__bf16)c.x; v[5]=(__bf16)c.y; v[6]=(__bf16)c.z; v[7]=(__bf16)c.w;
    *(bf16x8_t*)&sA[row * 256 + SWZ(ch, row) * 8] = v;
  }
  __syncthreads();

  f32x4 acc[4][4];
#pragma unroll
  for (int mi = 0; mi < 4; ++mi)
#pragma unroll
    for (int ni = 0; ni < 4; ++ni)
#pragma unroll
      for (int r = 0; r < 4; ++r) acc[mi][ni][r] = 0.f;

#pragma unroll
  for (int kc8 = 0; kc8 < 8; ++kc8) {     // NO barriers in K-loop
    bf16x8_t af[4], bfr[4];
#pragma unroll
    for (int mi = 0; mi < 4; ++mi) {
      int row = mi * 16 + m_l;
      int c   = kc8 * 4 + quad;
      af[mi] = *(const bf16x8_t*)&sA[row * 256 + SWZ(c, row) * 8];
    }
#pragma unroll
    for (int ni = 0; ni < 4; ++ni) {
      int n = wave * 64 + ni * 16 + m_l;
      bfr[ni] = *(const bf16x8_t*)(BT + (size_t)n * 256 + kc8 * 32 + quad * 8);
    }
#pragma unroll
    for (int mi = 0; mi < 4; ++mi)
#pragma unroll
      for (int ni = 0; ni < 4; ++ni)
        acc[mi][ni] = __builtin_amdgcn_mfma_f32_16x16x32_bf16(af[mi], bfr[ni], acc[mi][ni], 0, 0, 0);
  }
  __syncthreads();   // done reading sA; reuse as output stash

  // stash bf16 64x256 tile into LDS (swizzled)
  __bf16* sT = sA;
#pragma unroll
  for (int mi = 0; mi < 4; ++mi)
#pragma unroll
    for (int ni = 0; ni < 4; ++ni)
#pragma unroll
      for (int r = 0; r < 4; ++r) {
        int row = mi * 16 + quad * 4 + r;
        int col = wave * 64 + ni * 16 + m_l;
        sT[row * 256 + SWZ(col >> 3, row) * 8 + (col & 7)] = (__bf16)acc[mi][ni][r];
      }
  __syncthreads();

  // coalesced uB write from LDS
#pragma unroll
  for (int i = 0; i < 8; ++i) {
    int s   = tid + i * 256;
    int row = s >> 5, ch = s & 31;
    *(bf16x8_t*)(uB + (size_t)(m0 + row) * 256 + ch * 8) =
        *(const bf16x8_t*)&sT[row * 256 + SWZ(ch, row) * 8];
  }

  // fused scan_partial: 2 chunks x 128 complex states = 256 scans, one per thread
  {
    int k   = tid & 127;
    int chl = tid >> 7;               // 0..1
    float cc = Aarr[4 * k], sv = Aarr[4 * k + 1];
    float hr = 0.f, hi = 0.f;
#pragma unroll 8
    for (int j = 0; j < LC; ++j) {
      int row = chl * 32 + j;
      bf16x2_t v2 = *(const bf16x2_t*)&sT[row * 256 + SWZ(k >> 2, row) * 8 + ((2 * k) & 7)];
      float t = fmaf(hr, cc, fmaf(-hi, sv, (float)v2[0]));
      hi      = fmaf(hr, sv, fmaf( hi, cc, (float)v2[1]));
      hr = t;
    }
    int chg = (t0 >> 5) + chl;
    P[((size_t)b * NCHUNK + chg) * KHALF + k] = make_float2(hr, hi);
  }
}

// ---------------- GEMM2: carry from P (in-block), replay in LDS, y = X @ C ----------------
// Carry loop is wave-uniform (chg depends only on block/chl), P is L2-resident,
// and the ~chg-step dependent FMA chain overlaps with LDS staging of other waves.
__global__ __launch_bounds__(256) void gemm2_fused(
    const __bf16* __restrict__ uB, const float* __restrict__ Aarr,
    const float* __restrict__ x0, const float2* __restrict__ P,
    const __bf16* __restrict__ CT,
    float* __restrict__ state_out, float* __restrict__ Y) {
  __shared__ __align__(16) __bf16 sX[64 * 256];   // 32 KB

  const int tid  = threadIdx.x;
  const int lane = tid & 63;
  const int wave = tid >> 6;
  const int m_l  = lane & 15, quad = lane >> 4;
  const int m0   = blockIdx.x * 64;
  const int b    = m0 >> 12;
  const int t0   = m0 & 4095;

  // stage uB -> sX (swizzled), uB read exactly once
#pragma unroll
  for (int i = 0; i < 8; ++i) {
    int s   = tid + i * 256;
    int row = s >> 5, ch = s & 31;
    *(bf16x8_t*)&sX[row * 256 + SWZ(ch, row) * 8] =
        *(const bf16x8_t*)(uB + (size_t)(m0 + row) * 256 + ch * 8);
  }

  // per-thread carry-in from P: h = x0 advanced through chunks [0, chg) with w32.
  const int k   = tid & 127;
  const int chl = tid >> 7;
  const int chg = (t0 >> 5) + chl;
  const float cc = Aarr[4 * k], sv = Aarr[4 * k + 1];
  float carry_r, carry_i;
  {
    float wr = cc, wi = sv;                 // w^32 via 5 squarings
#pragma unroll
    for (int i = 0; i < 5; ++i) { float nr = wr*wr - wi*wi; wi = 2.f*wr*wi; wr = nr; }
    float hr = x0[b * 256 + 2 * k], hi = x0[b * 256 + 2 * k + 1];
    const float2* pp = P + (size_t)b * NCHUNK * KHALF + k;
#pragma unroll 4
    for (int ch = 0; ch < chg; ++ch) {      // wave-uniform trip count
      float2 pv = pp[(size_t)ch * KHALF];
      float t = fmaf(hr, wr, fmaf(-hi, wi, pv.x));
      hi      = fmaf(hr, wi, fmaf( hi, wr, pv.y));
      hr = t;
    }
    carry_r = hr; carry_i = hi;
  }
  __syncthreads();

  // in-LDS scan replay: 2 chunks x 128 k, one per thread (disjoint RMW)
  {
    float hr = carry_r, hi = carry_i;
#pragma unroll 8
    for (int j = 0; j < LC; ++j) {
      int row = chl * 32 + j;
      int idx = row * 256 + SWZ(k >> 2, row) * 8 + ((2 * k) & 7);
      bf16x2_t v2 = *(const bf16x2_t*)&sX[idx];
      float t = fmaf(hr, cc, fmaf(-hi, sv, (float)v2[0]));
      hi      = fmaf(hr, sv, fmaf( hi, cc, (float)v2[1]));
      hr = t;
      bf16x2_t o; o[0] = (__bf16)hr; o[1] = (__bf16)hi;
      *(bf16x2_t*)&sX[idx] = o;
    }
    if (t0 == 4032 && chl == 1) {           // last panel of batch b: x[b, 4095]
      state_out[b * 256 + 2 * k]     = hr;
      state_out[b * 256 + 2 * k + 1] = hi;
    }
  }
  __syncthreads();

  f32x4 acc[4][4];
#pragma unroll
  for (int mi = 0; mi < 4; ++mi)
#pragma unroll
    for (int ni = 0; ni < 4; ++ni)
#pragma unroll
      for (int r = 0; r < 4; ++r) acc[mi][ni][r] = 0.f;

#pragma unroll
  for (int kc8 = 0; kc8 < 8; ++kc8) {     // barrier-free K-loop
    bf16x8_t af[4], bfr[4];
#pragma unroll
    for (int mi = 0; mi < 4; ++mi) {
      int row = mi * 16 + m_l;
      int c   = kc8 * 4 + quad;
      af[mi] = *(const bf16x8_t*)&sX[row * 256 + SWZ(c, row) * 8];
    }
#pragma unroll
    for (int ni = 0; ni < 4; ++ni) {
      int n = wave * 64 + ni * 16 + m_l;
      bfr[ni] = *(const bf16x8_t*)(CT + (size_t)n * 256 + kc8 * 32 + quad * 8);
    }
#pragma unroll
    for (int mi = 0; mi < 4; ++mi)
#pragma unroll
      for (int ni = 0; ni < 4; ++ni)
        acc[mi][ni] = __builtin_amdgcn_mfma_f32_16x16x32_bf16(af[mi], bfr[ni], acc[mi][ni], 0, 0, 0);
  }

#pragma unroll
  for (int mi = 0; mi < 4; ++mi)
#pragma unroll
    for (int ni = 0; ni < 4; ++ni)
#pragma unroll
      for (int r = 0; r < 4; ++r) {
        int row = m0 + mi * 16 + quad * 4 + r;
        int col = wave * 64 + ni * 16 + m_l;
        Y[(size_t)row * 256 + col] = acc[mi][ni][r];
      }
}

extern "C" void kernel_launch(void* const* d_in, const int* in_sizes, int n_in,
                              void* d_out, int out_size, void* d_ws, size_t ws_size,
                              hipStream_t stream) {
  const float* u  = (const float*)d_in[0];
  const float* x0 = (const float*)d_in[1];
  const float* A  = (const float*)d_in[2];
  const float* B  = (const float*)d_in[3];
  const float* C  = (const float*)d_in[4];

  float* y         = (float*)d_out;
  float* state_out = y + (size_t)MTOT * 256;

  char* ws = (char*)d_ws;
  __bf16* BT = (__bf16*)ws;  ws += 256 * 256 * 2;
  __bf16* CT = (__bf16*)ws;  ws += 256 * 256 * 2;
  __bf16* uB = (__bf16*)ws;  ws += (size_t)MTOT * 256 * 2;
  float2* P  = (float2*)ws;  ws += (size_t)BATCH * NCHUNK * KHALF * sizeof(float2);

  transpose_bc<<<dim3(256, 2), 256, 0, stream>>>(B, C, BT, CT);
  gemm1_fused<<<dim3(MTOT / 64), 256, 0, stream>>>(u, BT, A, uB, P);
  gemm2_fused<<<dim3(MTOT / 64), 256, 0, stream>>>(uB, A, x0, P, CT, state_out, y);
}